// Round 7
// baseline (258.869 us; speedup 1.0000x reference)
//
#include <hip/hip_runtime.h>
#include <hip/hip_bf16.h>

#define TOK 8192
#define CDIM 768
#define NH 12
#define HD 64
#define QKV_N 2304
// 0.125 * log2(e): QK^T scale folded into Q, softmax runs in exp2 domain
#define QSCALE 0.18033688011f

typedef __attribute__((ext_vector_type(8))) short bf16x8;
typedef __attribute__((ext_vector_type(4))) float f32x4;
typedef unsigned short ushort_t;

__device__ __forceinline__ ushort_t f2bf(float f) {
  unsigned u = __float_as_uint(f);
  u += 0x7fffu + ((u >> 16) & 1u);
  return (ushort_t)(u >> 16);
}

__device__ __forceinline__ f32x4 mfma16(bf16x8 a, bf16x8 b, f32x4 c) {
  return __builtin_amdgcn_mfma_f32_16x16x32_bf16(a, b, c, 0, 0, 0);
}

// XOR swizzle for 8-chunk (64-col) bf16 LDS rows
__device__ __forceinline__ int swz(int r) { return (r ^ (r >> 3)) & 7; }
// 16-chunk (128-col) variant: XOR low 3 bits, keep bit 3
__device__ __forceinline__ int pos16(int c, int r) {
  return (c & 8) | ((c ^ swz(r)) & 7);
}

__device__ __forceinline__ void gload16(const void* g, void* l) {
  __builtin_amdgcn_global_load_lds(
      (const __attribute__((address_space(1))) unsigned int*)g,
      (__attribute__((address_space(3))) unsigned int*)l, 16, 0, 0);
}

// ---------------- LayerNorm: 1 block per token, fp32 stats, bf16 out ----------
__global__ __launch_bounds__(256) void ln_kernel(const float* __restrict__ x,
                                                 const float* __restrict__ gamma,
                                                 const float* __restrict__ beta,
                                                 ushort_t* __restrict__ xn) {
  int t = blockIdx.x;
  const float* row = x + (size_t)t * CDIM;
  float v[3];
  float s = 0.f, s2 = 0.f;
#pragma unroll
  for (int i = 0; i < 3; i++) {
    v[i] = row[threadIdx.x + 256 * i];
    s += v[i];
    s2 += v[i] * v[i];
  }
#pragma unroll
  for (int off = 32; off; off >>= 1) {
    s += __shfl_xor(s, off);
    s2 += __shfl_xor(s2, off);
  }
  __shared__ float red[8];
  int wid = threadIdx.x >> 6, lane = threadIdx.x & 63;
  if (lane == 0) { red[wid] = s; red[wid + 4] = s2; }
  __syncthreads();
  s = red[0] + red[1] + red[2] + red[3];
  s2 = red[4] + red[5] + red[6] + red[7];
  float mu = s * (1.f / CDIM);
  float var = s2 * (1.f / CDIM) - mu * mu;
  float rstd = rsqrtf(var + 1e-5f);
  ushort_t* orow = xn + (size_t)t * CDIM;
#pragma unroll
  for (int i = 0; i < 3; i++) {
    int c = threadIdx.x + 256 * i;
    orow[c] = f2bf((v[i] - mu) * rstd * gamma[c] + beta[c]);
  }
}

// -------- Weight transpose to bf16: wt[z][n][k] = W_z[k][n] ------------------
__global__ __launch_bounds__(256) void wtrans_kernel(const float* __restrict__ Wq,
                                                     const float* __restrict__ Wk,
                                                     const float* __restrict__ Wv,
                                                     const float* __restrict__ Wo,
                                                     ushort_t* __restrict__ wt) {
  const float* W = (blockIdx.z == 0) ? Wq : (blockIdx.z == 1) ? Wk
                   : (blockIdx.z == 2) ? Wv : Wo;
  __shared__ float tile[32][33];
  int tr = blockIdx.y, tc = blockIdx.x;
  int tx = threadIdx.x, ty = threadIdx.y;
#pragma unroll
  for (int j = 0; j < 4; j++) {
    int k = tr * 32 + ty + j * 8;
    tile[ty + j * 8][tx] = W[(size_t)k * CDIM + tc * 32 + tx];
  }
  __syncthreads();
  ushort_t* o = wt + (size_t)blockIdx.z * CDIM * CDIM;
#pragma unroll
  for (int j = 0; j < 4; j++) {
    int n = tc * 32 + ty + j * 8;
    o[(size_t)n * CDIM + tr * 32 + tx] = f2bf(tile[tx][ty + j * 8]);
  }
}

// -------- GEMM (m97 structure + T2 swizzle): C = A Bt^T + epilogue -----------
// MODE 0: QKV fused (N=2304), bf16 out; Q third gets (+bias+pos)*QSCALE
// MODE 1: out-proj (N=768), fp32 out, +bias +fp32 residual
template <int MODE>
__global__ __launch_bounds__(256) void gemm_kernel(
    const ushort_t* __restrict__ A, const ushort_t* __restrict__ Bt,
    const float* __restrict__ b0, const float* __restrict__ b1,
    const float* __restrict__ b2, const float* __restrict__ extra,
    void* __restrict__ outp) {
  __shared__ __align__(16) ushort_t lds_a[128 * 64];
  __shared__ __align__(16) ushort_t lds_b[128 * 64];
  const int NB = (MODE == 0) ? 18 : 6;
  // XCD-chunked swizzle (nwg % 8 == 0 in both modes)
  int lin = blockIdx.y * NB + blockIdx.x;
  int nl = (lin & 7) * (NB * 8) + (lin >> 3);
  const int bn = nl % NB, bm = nl / NB;

  const int tid = threadIdx.x;
  const int lane = tid & 63, wid = tid >> 6;
  const int wr = wid >> 1, wc = wid & 1;
  const int l16 = lane & 15, lg = lane >> 4;
  f32x4 acc[4][4] = {};

  // hoisted swizzled read offsets
  int aoff[2][4], boff[2][4];
#pragma unroll
  for (int kk = 0; kk < 2; kk++) {
#pragma unroll
    for (int mi = 0; mi < 4; mi++) {
      int r = wr * 64 + mi * 16 + l16;
      aoff[kk][mi] = r * 64 + (((kk * 4 + lg) ^ swz(r)) & 7) * 8;
    }
#pragma unroll
    for (int ni = 0; ni < 4; ni++) {
      int r = wc * 64 + ni * 16 + l16;
      boff[kk][ni] = r * 64 + (((kk * 4 + lg) ^ swz(r)) & 7) * 8;
    }
  }

  for (int k0 = 0; k0 < CDIM; k0 += 64) {
#pragma unroll
    for (int i = 0; i < 4; i++) {
      int slot = i * 256 + tid;           // 1024 chunks of 16B per tile
      int row = slot >> 3, j = slot & 7;
      int c8 = ((j ^ swz(row)) & 7) * 8;  // pre-swizzled source column
      gload16(&A[(size_t)(bm * 128 + row) * CDIM + k0 + c8], &lds_a[slot * 8]);
      gload16(&Bt[(size_t)(bn * 128 + row) * CDIM + k0 + c8], &lds_b[slot * 8]);
    }
    __syncthreads();
#pragma unroll
    for (int kk = 0; kk < 2; kk++) {
      bf16x8 af[4], bfr[4];
#pragma unroll
      for (int mi = 0; mi < 4; mi++)
        af[mi] = *reinterpret_cast<const bf16x8*>(&lds_a[aoff[kk][mi]]);
#pragma unroll
      for (int ni = 0; ni < 4; ni++)
        bfr[ni] = *reinterpret_cast<const bf16x8*>(&lds_b[boff[kk][ni]]);
#pragma unroll
      for (int mi = 0; mi < 4; mi++)
#pragma unroll
        for (int ni = 0; ni < 4; ni++)
          acc[mi][ni] = mfma16(af[mi], bfr[ni], acc[mi][ni]);
    }
    __syncthreads();
  }

#pragma unroll
  for (int mi = 0; mi < 4; mi++)
#pragma unroll
    for (int ni = 0; ni < 4; ni++)
#pragma unroll
      for (int r = 0; r < 4; r++) {
        int grow = bm * 128 + wr * 64 + mi * 16 + 4 * lg + r;
        int gcol = bn * 128 + wc * 64 + ni * 16 + l16;
        float v = acc[mi][ni][r];
        if (MODE == 0) {
          if (gcol < 768) {
            // Q: add bias + pos_embed, fold 1/sqrt(64)*log2(e) for exp2-softmax
            v = (v + b0[gcol] + extra[(size_t)grow * CDIM + gcol]) * QSCALE;
          } else if (gcol < 1536) {
            v += b1[gcol - 768];
          } else {
            v += b2[gcol - 1536];
          }
          ((ushort_t*)outp)[(size_t)grow * QKV_N + gcol] = f2bf(v);
        } else {
          v += b0[gcol] + extra[(size_t)grow * CDIM + gcol];
          ((float*)outp)[(size_t)grow * CDIM + gcol] = v;
        }
      }
}

// -------- Flash attention v6: KVBLK=128, exp2 softmax, tree reductions -------
// QBLK=64 (grid 1536), 4 waves x 16 q-rows. Swapped QK^T (lane owns q-row).
// 8 outer iters of 128 kv: halved barriers/shuffles/rescales vs v5.
// K: kf[2][8] direct-global, prefetched one tile ahead. V^T dbuf in LDS
// (16KB x2). P via wave-private 128-col swizzled LDS + v_cvt_pk_bf16_f32.
__global__ __launch_bounds__(256, 3) void attn_kernel(const ushort_t* __restrict__ QKV,
                                                      ushort_t* __restrict__ O) {
  // XCD-chunked swizzle over 1536 = 8 x 192: each XCD owns one batch b
  int lin = (blockIdx.z * NH + blockIdx.y) * 16 + blockIdx.x;
  int nl = (lin & 7) * 192 + (lin >> 3);
  const int qt = nl & 15;
  const int h = (nl >> 4) % NH;
  const int b = nl / 192;

  const int tid = threadIdx.x, lane = tid & 63, w = tid >> 6;
  const int l16 = lane & 15, lg = lane >> 4;
  const int tb = b * 1024 + qt * 64;
  const int co_q = h * HD, co_k = CDIM + h * HD, co_v = 2 * CDIM + h * HD;

  __shared__ __align__(16) ushort_t vt_lds[2][64 * 128];  // V^T [d][kv]
  __shared__ __align__(16) ushort_t p_lds[64 * 128];      // P [q][kv]

  // Q as B-fragment: rows q = w*16 + l16 (QSCALE folded in by QKV-GEMM)
  bf16x8 qf[2];
#pragma unroll
  for (int ds = 0; ds < 2; ds++)
    qf[ds] = *reinterpret_cast<const bf16x8*>(
        &QKV[(size_t)(tb + w * 16 + l16) * QKV_N + co_q + ds * 32 + 8 * lg]);

  const int myq = w * 16 + l16;  // this lane's softmax row (block-local)
  float m_sm = -1e30f, l_sm = 0.f;  // per-lane row stats, exp2 domain
  float m_acc[4];                    // stats in oacc-row layout (4*lg+r)
#pragma unroll
  for (int r = 0; r < 4; r++) m_acc[r] = -1e30f;
  f32x4 oacc[4] = {};

  // ---- hoisted LDS offsets ----
  int poff[8];  // P writes: col = ni*16 + 4*lg + r
#pragma unroll
  for (int ni = 0; ni < 8; ni++) {
    int c = ni * 2 + (lg >> 1);
    poff[ni] = myq * 128 + pos16(c, myq) * 8 + (lg & 1) * 4;
  }
  int paoff[4];  // P reads (A-frag): chunk = ks*4 + lg
#pragma unroll
  for (int ks = 0; ks < 4; ks++)
    paoff[ks] = myq * 128 + pos16(ks * 4 + lg, myq) * 8;
  int vboff[4][4];  // V^T reads (B-frag): row d = ni*16+l16
#pragma unroll
  for (int ks = 0; ks < 4; ks++)
#pragma unroll
    for (int ni = 0; ni < 4; ni++) {
      int d = ni * 16 + l16;
      vboff[ks][ni] = d * 128 + pos16(ks * 4 + lg, d) * 8;
    }

  // ---- V staging: thread owns 4 kv rows (kv0..kv0+3) x 8 d-elems ----
  const int kv0 = (tid >> 3) * 4, d0 = (tid & 7) * 8;
  int voff[8];
#pragma unroll
  for (int u = 0; u < 8; u++) {
    int d = d0 + u;
    voff[u] = d * 128 + pos16(kv0 >> 3, d) * 8 + (kv0 & 7);
  }
  const ushort_t* vsrc = QKV + (size_t)(b * 1024 + kv0) * QKV_N + co_v + d0;

  uint4 vr0, vr1, vr2, vr3;
  auto load_v = [&](int kt) {
    const ushort_t* p = vsrc + (size_t)kt * 128 * QKV_N;
    vr0 = *reinterpret_cast<const uint4*>(p);
    vr1 = *reinterpret_cast<const uint4*>(p + QKV_N);
    vr2 = *reinterpret_cast<const uint4*>(p + 2 * QKV_N);
    vr3 = *reinterpret_cast<const uint4*>(p + 3 * QKV_N);
  };
  auto write_v = [&](int buf) {
    const unsigned* w0 = reinterpret_cast<const unsigned*>(&vr0);
    const unsigned* w1 = reinterpret_cast<const unsigned*>(&vr1);
    const unsigned* w2 = reinterpret_cast<const unsigned*>(&vr2);
    const unsigned* w3 = reinterpret_cast<const unsigned*>(&vr3);
#pragma unroll
    for (int u = 0; u < 8; u++) {
      unsigned a = w0[u >> 1], c1 = w1[u >> 1];
      unsigned e = w2[u >> 1], g = w3[u >> 1];
      unsigned v01, v23;
      if (u & 1) {
        v01 = (a >> 16) | (c1 & 0xffff0000u);
        v23 = (e >> 16) | (g & 0xffff0000u);
      } else {
        v01 = (a & 0xffffu) | (c1 << 16);
        v23 = (e & 0xffffu) | (g << 16);
      }
      uint2 pk; pk.x = v01; pk.y = v23;
      *reinterpret_cast<uint2*>(&vt_lds[buf][voff[u]]) = pk;
    }
  };

  // ---- K fragments: direct from global (L2-hot), prefetched one tile ahead
  const ushort_t* kbase = QKV + (size_t)(b * 1024 + l16) * QKV_N + co_k + 8 * lg;
  bf16x8 kf[2][8];
  auto load_k = [&](int kt) {
#pragma unroll
    for (int ds = 0; ds < 2; ds++)
#pragma unroll
      for (int ni = 0; ni < 8; ni++)
        kf[ds][ni] = *reinterpret_cast<const bf16x8*>(
            kbase + ((size_t)kt * 128 + ni * 16) * QKV_N + ds * 32);
  };

  // prologue
  load_k(0);
  load_v(0);
  write_v(0);
  asm volatile("s_waitcnt lgkmcnt(0)" ::: "memory");
  __builtin_amdgcn_s_barrier();
  __builtin_amdgcn_sched_barrier(0);

  for (int kt = 0; kt < 8; kt++) {
    const int cur = kt & 1, nxt = cur ^ 1;
    if (kt < 7) load_v(kt + 1);  // issue early; consumed by write_v below

    // S^T = K Q^T : lane holds col q=l16, rows kv = ni*16 + 4*lg + r
    f32x4 st[8] = {};
    __builtin_amdgcn_s_setprio(1);
#pragma unroll
    for (int ds = 0; ds < 2; ds++)
#pragma unroll
      for (int ni = 0; ni < 8; ni++)
        st[ni] = mfma16(kf[ds][ni], qf[ds], st[ni]);
    __builtin_amdgcn_s_setprio(0);

    if (kt < 7) load_k(kt + 1);  // prefetch next K; latency hidden below

    // lane-local softmax over 32 kv values (tree) + 2 shfl_xor
    float t8[8];
#pragma unroll
    for (int ni = 0; ni < 8; ni++)
      t8[ni] = fmaxf(fmaxf(st[ni][0], st[ni][1]), fmaxf(st[ni][2], st[ni][3]));
    float ta = fmaxf(fmaxf(t8[0], t8[1]), fmaxf(t8[2], t8[3]));
    float tb2 = fmaxf(fmaxf(t8[4], t8[5]), fmaxf(t8[6], t8[7]));
    float tm = fmaxf(ta, tb2);
    tm = fmaxf(tm, __shfl_xor(tm, 16));
    tm = fmaxf(tm, __shfl_xor(tm, 32));
    float mnew = fmaxf(m_sm, tm);
    bool grew = tm > m_sm;

    // P = exp2(S - m), tree-summed
    float ps[8];
#pragma unroll
    for (int ni = 0; ni < 8; ni++) {
      float e0 = exp2f(st[ni][0] - mnew);
      float e1 = exp2f(st[ni][1] - mnew);
      float e2 = exp2f(st[ni][2] - mnew);
      float e3 = exp2f(st[ni][3] - mnew);
      st[ni][0] = e0; st[ni][1] = e1; st[ni][2] = e2; st[ni][3] = e3;
      ps[ni] = (e0 + e1) + (e2 + e3);
    }
    float sa = (ps[0] + ps[1]) + (ps[2] + ps[3]);
    float sb = (ps[4] + ps[5]) + (ps[6] + ps[7]);
    float psum = sa + sb;
    psum += __shfl_xor(psum, 16);
    psum += __shfl_xor(psum, 32);
    l_sm = l_sm * (grew ? exp2f(m_sm - mnew) : 1.0f) + psum;
    m_sm = mnew;

    // redistribute new max to oacc-row layout; rescale oacc (skip if no-op)
    if (__any(grew)) {
#pragma unroll
      for (int r = 0; r < 4; r++) {
        float mn = __shfl(mnew, 4 * lg + r);  // lane 4*lg+r owns row 4*lg+r
        float corr = exp2f(m_acc[r] - mn);
        m_acc[r] = mn;
#pragma unroll
        for (int ni = 0; ni < 4; ni++) oacc[ni][r] *= corr;
      }
    }

    // P -> LDS via v_cvt_pk_bf16_f32 (src0 -> low half), 8B stores, swizzled
#pragma unroll
    for (int ni = 0; ni < 8; ni++) {
      unsigned p01, p23;
      asm("v_cvt_pk_bf16_f32 %0, %1, %2" : "=v"(p01) : "v"(st[ni][0]), "v"(st[ni][1]));
      asm("v_cvt_pk_bf16_f32 %0, %1, %2" : "=v"(p23) : "v"(st[ni][2]), "v"(st[ni][3]));
      uint2 pk; pk.x = p01; pk.y = p23;
      *reinterpret_cast<uint2*>(&p_lds[poff[ni]]) = pk;
    }

    // O += P @ V  (pa: wave-private p_lds rows; vb: staged V^T)
#pragma unroll
    for (int ks = 0; ks < 4; ks++) {
      bf16x8 pa = *reinterpret_cast<const bf16x8*>(&p_lds[paoff[ks]]);
      bf16x8 vb[4];
#pragma unroll
      for (int ni = 0; ni < 4; ni++)
        vb[ni] = *reinterpret_cast<const bf16x8*>(&vt_lds[cur][vboff[ks][ni]]);
      __builtin_amdgcn_s_setprio(1);
#pragma unroll
      for (int ni = 0; ni < 4; ni++)
        oacc[ni] = mfma16(pa, vb[ni], oacc[ni]);
      __builtin_amdgcn_s_setprio(0);
    }

    if (kt < 7) write_v(nxt);
    asm volatile("s_waitcnt lgkmcnt(0)" ::: "memory");
    __builtin_amdgcn_s_barrier();
    __builtin_amdgcn_sched_barrier(0);
  }

  // epilogue: divide by row-sum (redistributed to oacc-row layout) and store
#pragma unroll
  for (int r = 0; r < 4; r++) {
    float lr = __shfl(l_sm, 4 * lg + r);
    float inv = 1.f / lr;
    int grow = tb + w * 16 + 4 * lg + r;
#pragma unroll
    for (int ni = 0; ni < 4; ni++) {
      int gcol = h * HD + ni * 16 + l16;
      O[(size_t)grow * CDIM + gcol] = f2bf(oacc[ni][r] * inv);
    }
  }
}

extern "C" void kernel_launch(void* const* d_in, const int* in_sizes, int n_in,
                              void* d_out, int out_size, void* d_ws, size_t ws_size,
                              hipStream_t stream) {
  const float* x     = (const float*)d_in[0];
  const float* pos   = (const float*)d_in[1];
  const float* gamma = (const float*)d_in[2];
  const float* beta  = (const float*)d_in[3];
  const float* Wq    = (const float*)d_in[4];
  const float* bq    = (const float*)d_in[5];
  const float* Wk    = (const float*)d_in[6];
  const float* bk    = (const float*)d_in[7];
  const float* Wv    = (const float*)d_in[8];
  const float* bv    = (const float*)d_in[9];
  const float* Wo    = (const float*)d_in[10];
  const float* bo    = (const float*)d_in[11];
  float* out = (float*)d_out;

  ushort_t* xn   = (ushort_t*)d_ws;                    // 8192*768
  ushort_t* wt   = xn + (size_t)TOK * CDIM;            // 3072*768 (q,k,v,o transposed)
  ushort_t* qkv  = wt + (size_t)3072 * CDIM;           // 8192*2304
  ushort_t* aout = qkv + (size_t)TOK * QKV_N;          // 8192*768

  ln_kernel<<<TOK, 256, 0, stream>>>(x, gamma, beta, xn);
  wtrans_kernel<<<dim3(24, 24, 4), dim3(32, 8), 0, stream>>>(Wq, Wk, Wv, Wo, wt);
  gemm_kernel<0><<<dim3(18, 64), 256, 0, stream>>>(xn, wt, bq, bk, bv, pos, qkv);
  attn_kernel<<<dim3(16, NH, 8), 256, 0, stream>>>(qkv, aout);
  gemm_kernel<1><<<dim3(6, 64), 256, 0, stream>>>(aout, wt + (size_t)QKV_N * CDIM,
                                                  bo, nullptr, nullptr, x, out);
}

// Round 8
// 214.018 us; speedup vs baseline: 1.2096x; 1.2096x over previous
//
#include <hip/hip_runtime.h>
#include <hip/hip_bf16.h>

#define TOK 8192
#define CDIM 768
#define NH 12
#define HD 64
#define QKV_N 2304
// 0.125 * log2(e): QK^T scale folded into Q, softmax runs in exp2 domain
#define QSCALE 0.18033688011f

typedef __attribute__((ext_vector_type(8))) short bf16x8;
typedef __attribute__((ext_vector_type(4))) float f32x4;
typedef unsigned short ushort_t;

__device__ __forceinline__ ushort_t f2bf(float f) {
  unsigned u = __float_as_uint(f);
  u += 0x7fffu + ((u >> 16) & 1u);
  return (ushort_t)(u >> 16);
}

__device__ __forceinline__ f32x4 mfma16(bf16x8 a, bf16x8 b, f32x4 c) {
  return __builtin_amdgcn_mfma_f32_16x16x32_bf16(a, b, c, 0, 0, 0);
}

// XOR swizzle for 8-chunk (64-col) bf16 LDS rows
__device__ __forceinline__ int swz(int r) { return (r ^ (r >> 3)) & 7; }

__device__ __forceinline__ void gload16(const void* g, void* l) {
  __builtin_amdgcn_global_load_lds(
      (const __attribute__((address_space(1))) unsigned int*)g,
      (__attribute__((address_space(3))) unsigned int*)l, 16, 0, 0);
}

// ---------------- LayerNorm: 1 block per token, fp32 stats, bf16 out ----------
__global__ __launch_bounds__(256) void ln_kernel(const float* __restrict__ x,
                                                 const float* __restrict__ gamma,
                                                 const float* __restrict__ beta,
                                                 ushort_t* __restrict__ xn) {
  int t = blockIdx.x;
  const float* row = x + (size_t)t * CDIM;
  float v[3];
  float s = 0.f, s2 = 0.f;
#pragma unroll
  for (int i = 0; i < 3; i++) {
    v[i] = row[threadIdx.x + 256 * i];
    s += v[i];
    s2 += v[i] * v[i];
  }
#pragma unroll
  for (int off = 32; off; off >>= 1) {
    s += __shfl_xor(s, off);
    s2 += __shfl_xor(s2, off);
  }
  __shared__ float red[8];
  int wid = threadIdx.x >> 6, lane = threadIdx.x & 63;
  if (lane == 0) { red[wid] = s; red[wid + 4] = s2; }
  __syncthreads();
  s = red[0] + red[1] + red[2] + red[3];
  s2 = red[4] + red[5] + red[6] + red[7];
  float mu = s * (1.f / CDIM);
  float var = s2 * (1.f / CDIM) - mu * mu;
  float rstd = rsqrtf(var + 1e-5f);
  ushort_t* orow = xn + (size_t)t * CDIM;
#pragma unroll
  for (int i = 0; i < 3; i++) {
    int c = threadIdx.x + 256 * i;
    orow[c] = f2bf((v[i] - mu) * rstd * gamma[c] + beta[c]);
  }
}

// -------- Weight transpose to bf16: wt[z][n][k] = W_z[k][n] ------------------
__global__ __launch_bounds__(256) void wtrans_kernel(const float* __restrict__ Wq,
                                                     const float* __restrict__ Wk,
                                                     const float* __restrict__ Wv,
                                                     const float* __restrict__ Wo,
                                                     ushort_t* __restrict__ wt) {
  const float* W = (blockIdx.z == 0) ? Wq : (blockIdx.z == 1) ? Wk
                   : (blockIdx.z == 2) ? Wv : Wo;
  __shared__ float tile[32][33];
  int tr = blockIdx.y, tc = blockIdx.x;
  int tx = threadIdx.x, ty = threadIdx.y;
#pragma unroll
  for (int j = 0; j < 4; j++) {
    int k = tr * 32 + ty + j * 8;
    tile[ty + j * 8][tx] = W[(size_t)k * CDIM + tc * 32 + tx];
  }
  __syncthreads();
  ushort_t* o = wt + (size_t)blockIdx.z * CDIM * CDIM;
#pragma unroll
  for (int j = 0; j < 4; j++) {
    int n = tc * 32 + ty + j * 8;
    o[(size_t)n * CDIM + tr * 32 + tx] = f2bf(tile[tx][ty + j * 8]);
  }
}

// -------- GEMM v3: T2 swizzle + overlapped double-buffer (issue-early) -------
// Loop: STAGE(t+1 -> buf^1) issued at top; compute tile t from buf; single
// vmcnt(0)+s_barrier at bottom (t+1 HBM latency hides under compute).
// MODE 0: QKV fused (N=2304), bf16 out; Q third gets (+bias+pos)*QSCALE
// MODE 1: out-proj (N=768), fp32 out, +bias +fp32 residual
template <int MODE>
__global__ __launch_bounds__(256) void gemm_kernel(
    const ushort_t* __restrict__ A, const ushort_t* __restrict__ Bt,
    const float* __restrict__ b0, const float* __restrict__ b1,
    const float* __restrict__ b2, const float* __restrict__ extra,
    void* __restrict__ outp) {
  __shared__ __align__(16) ushort_t lds_a[2][128 * 64];
  __shared__ __align__(16) ushort_t lds_b[2][128 * 64];
  const int NB = (MODE == 0) ? 18 : 6;
  // XCD-chunked swizzle (nwg % 8 == 0 in both modes)
  int lin = blockIdx.y * NB + blockIdx.x;
  int nl = (lin & 7) * (NB * 8) + (lin >> 3);
  const int bn = nl % NB, bm = nl / NB;

  const int tid = threadIdx.x;
  const int lane = tid & 63, wid = tid >> 6;
  const int wr = wid >> 1, wc = wid & 1;
  const int l16 = lane & 15, lg = lane >> 4;
  f32x4 acc[4][4] = {};

  // hoisted swizzled read offsets
  int aoff[2][4], boff[2][4];
#pragma unroll
  for (int kk = 0; kk < 2; kk++) {
#pragma unroll
    for (int mi = 0; mi < 4; mi++) {
      int r = wr * 64 + mi * 16 + l16;
      aoff[kk][mi] = r * 64 + (((kk * 4 + lg) ^ swz(r)) & 7) * 8;
    }
#pragma unroll
    for (int ni = 0; ni < 4; ni++) {
      int r = wc * 64 + ni * 16 + l16;
      boff[kk][ni] = r * 64 + (((kk * 4 + lg) ^ swz(r)) & 7) * 8;
    }
  }

  // hoisted staging addresses (per-thread, 4 chunk slots)
  const int srow = tid >> 1, sj = tid & 1;  // base pattern regenerated per i
  (void)srow; (void)sj;

  auto stage = [&](int buf, int k0) {
#pragma unroll
    for (int i = 0; i < 4; i++) {
      int slot = i * 256 + tid;           // 1024 chunks of 16B per tile
      int row = slot >> 3, j = slot & 7;
      int c8 = ((j ^ swz(row)) & 7) * 8;  // pre-swizzled source column
      gload16(&A[(size_t)(bm * 128 + row) * CDIM + k0 + c8], &lds_a[buf][slot * 8]);
      gload16(&Bt[(size_t)(bn * 128 + row) * CDIM + k0 + c8], &lds_b[buf][slot * 8]);
    }
  };

  // prologue: stage tile 0, drain, barrier
  stage(0, 0);
  asm volatile("s_waitcnt vmcnt(0)" ::: "memory");
  __builtin_amdgcn_s_barrier();
  __builtin_amdgcn_sched_barrier(0);

  int cur = 0;
#pragma unroll 2
  for (int t = 0; t < 12; t++) {
    if (t < 11) stage(cur ^ 1, (t + 1) * 64);  // issue next tile early
#pragma unroll
    for (int kk = 0; kk < 2; kk++) {
      bf16x8 af[4], bfr[4];
#pragma unroll
      for (int mi = 0; mi < 4; mi++)
        af[mi] = *reinterpret_cast<const bf16x8*>(&lds_a[cur][aoff[kk][mi]]);
#pragma unroll
      for (int ni = 0; ni < 4; ni++)
        bfr[ni] = *reinterpret_cast<const bf16x8*>(&lds_b[cur][boff[kk][ni]]);
      __builtin_amdgcn_s_setprio(1);
#pragma unroll
      for (int mi = 0; mi < 4; mi++)
#pragma unroll
        for (int ni = 0; ni < 4; ni++)
          acc[mi][ni] = mfma16(af[mi], bfr[ni], acc[mi][ni]);
      __builtin_amdgcn_s_setprio(0);
    }
    // wait late: t+1 loads landed during compute; all reads of cur done
    asm volatile("s_waitcnt vmcnt(0) lgkmcnt(0)" ::: "memory");
    __builtin_amdgcn_s_barrier();
    __builtin_amdgcn_sched_barrier(0);
    cur ^= 1;
  }

#pragma unroll
  for (int mi = 0; mi < 4; mi++)
#pragma unroll
    for (int ni = 0; ni < 4; ni++)
#pragma unroll
      for (int r = 0; r < 4; r++) {
        int grow = bm * 128 + wr * 64 + mi * 16 + 4 * lg + r;
        int gcol = bn * 128 + wc * 64 + ni * 16 + l16;
        float v = acc[mi][ni][r];
        if (MODE == 0) {
          if (gcol < 768) {
            // Q: add bias + pos_embed, fold 1/sqrt(64)*log2(e) for exp2-softmax
            v = (v + b0[gcol] + extra[(size_t)grow * CDIM + gcol]) * QSCALE;
          } else if (gcol < 1536) {
            v += b1[gcol - 768];
          } else {
            v += b2[gcol - 1536];
          }
          ((ushort_t*)outp)[(size_t)grow * QKV_N + gcol] = f2bf(v);
        } else {
          v += b0[gcol] + extra[(size_t)grow * CDIM + gcol];
          ((float*)outp)[(size_t)grow * CDIM + gcol] = v;
        }
      }
}

// -------- Flash attention v7: v5 structure + exp2/tree/cvt_pk VALU cuts ------
// KVBLK=64 (proven no-spill, VGPR ~64). Swapped QK^T, lane-local softmax in
// exp2 domain (QSCALE folded into Q), tree psum, cvt_pk P-pack.
__global__ __launch_bounds__(256, 4) void attn_kernel(const ushort_t* __restrict__ QKV,
                                                      ushort_t* __restrict__ O) {
  // XCD-chunked swizzle over 1536 = 8 x 192: each XCD owns one batch b
  int lin = (blockIdx.z * NH + blockIdx.y) * 16 + blockIdx.x;
  int nl = (lin & 7) * 192 + (lin >> 3);
  const int qt = nl & 15;
  const int h = (nl >> 4) % NH;
  const int b = nl / 192;

  const int tid = threadIdx.x, lane = tid & 63, w = tid >> 6;
  const int l16 = lane & 15, lg = lane >> 4;
  const int tb = b * 1024 + qt * 64;
  const int co_q = h * HD, co_k = CDIM + h * HD, co_v = 2 * CDIM + h * HD;

  __shared__ __align__(16) ushort_t vt_lds[2][64 * 64];
  __shared__ __align__(16) ushort_t p_lds[64 * 64];

  // Q as B-fragment: rows q = w*16 + l16 (QSCALE folded in by QKV-GEMM)
  bf16x8 qf[2];
#pragma unroll
  for (int ds = 0; ds < 2; ds++)
    qf[ds] = *reinterpret_cast<const bf16x8*>(
        &QKV[(size_t)(tb + w * 16 + l16) * QKV_N + co_q + ds * 32 + 8 * lg]);

  const int myq = w * 16 + l16;  // this lane's softmax row (block-local)
  const int sq = swz(myq);
  float m_sm = -1e30f, l_sm = 0.f;  // per-lane row stats, exp2 domain
  float m_acc[4];                    // stats in oacc-row layout (4*lg+r)
#pragma unroll
  for (int r = 0; r < 4; r++) m_acc[r] = -1e30f;
  f32x4 oacc[4] = {};

  // ---- hoisted LDS offsets (loop-invariant) ----
  int poff[4];
#pragma unroll
  for (int ni = 0; ni < 4; ni++)
    poff[ni] = myq * 64 + (lg & 1) * 4 + (((ni * 2 + (lg >> 1)) ^ sq) & 7) * 8;
  int paoff[2];
#pragma unroll
  for (int ks = 0; ks < 2; ks++)
    paoff[ks] = myq * 64 + (((ks * 4 + lg) ^ sq) & 7) * 8;
  int vboff[2][4];
#pragma unroll
  for (int ks = 0; ks < 2; ks++)
#pragma unroll
    for (int ni = 0; ni < 4; ni++) {
      int d = ni * 16 + l16;
      vboff[ks][ni] = d * 64 + (((ks * 4 + lg) ^ swz(d)) & 7) * 8;
    }

  // ---- paired-kv V staging: thread owns rows (kv0, kv0+1), d-chunk d0..d0+7
  const int kv0 = (tid >> 3) * 2, d0 = (tid & 7) * 8;
  const int sV = ((kv0 >> 3) ^ (d0 >> 3)) & 7;
  int voff[8];
#pragma unroll
  for (int u = 0; u < 8; u++)
    voff[u] = (d0 + u) * 64 + ((sV ^ u) & 7) * 8 + (kv0 & 7);
  const ushort_t* vsrc = QKV + (size_t)(b * 1024 + kv0) * QKV_N + co_v + d0;

  uint4 vr0, vr1;
  auto load_v = [&](int kt) {
    vr0 = *reinterpret_cast<const uint4*>(vsrc + (size_t)kt * 64 * QKV_N);
    vr1 = *reinterpret_cast<const uint4*>(vsrc + (size_t)kt * 64 * QKV_N + QKV_N);
  };
  auto write_v = [&](int buf) {
    const unsigned* w0 = reinterpret_cast<const unsigned*>(&vr0);
    const unsigned* w1 = reinterpret_cast<const unsigned*>(&vr1);
#pragma unroll
    for (int u = 0; u < 8; u++) {
      unsigned a = w0[u >> 1], c = w1[u >> 1];
      unsigned val = (u & 1) ? ((a >> 16) | (c & 0xffff0000u))
                             : ((a & 0xffffu) | (c << 16));
      *reinterpret_cast<unsigned*>(&vt_lds[buf][voff[u]]) = val;
    }
  };

  // ---- K fragments: direct from global (L2-hot), prefetched one tile ahead
  const ushort_t* kbase = QKV + (size_t)(b * 1024 + l16) * QKV_N + co_k + 8 * lg;
  bf16x8 kf[2][4];
  auto load_k = [&](int kt) {
#pragma unroll
    for (int ds = 0; ds < 2; ds++)
#pragma unroll
      for (int ni = 0; ni < 4; ni++)
        kf[ds][ni] = *reinterpret_cast<const bf16x8*>(
            kbase + ((size_t)kt * 64 + ni * 16) * QKV_N + ds * 32);
  };

  // prologue
  load_k(0);
  load_v(0);
  write_v(0);
  asm volatile("s_waitcnt lgkmcnt(0)" ::: "memory");
  __builtin_amdgcn_s_barrier();
  __builtin_amdgcn_sched_barrier(0);

  for (int kt = 0; kt < 16; kt++) {
    const int cur = kt & 1, nxt = cur ^ 1;
    if (kt < 15) load_v(kt + 1);  // issue early; consumed by write_v below

    // S^T = K Q^T : lane holds col q=l16, rows kv = ni*16 + 4*lg + r
    f32x4 st[4] = {};
    __builtin_amdgcn_s_setprio(1);
#pragma unroll
    for (int ds = 0; ds < 2; ds++)
#pragma unroll
      for (int ni = 0; ni < 4; ni++)
        st[ni] = mfma16(kf[ds][ni], qf[ds], st[ni]);
    __builtin_amdgcn_s_setprio(0);

    if (kt < 15) load_k(kt + 1);  // prefetch next K; latency hidden below

    // lane-local softmax over 16 kv values + 2 shfl_xor (exp2 domain)
    float t0 = fmaxf(fmaxf(st[0][0], st[0][1]), fmaxf(st[0][2], st[0][3]));
    float t1 = fmaxf(fmaxf(st[1][0], st[1][1]), fmaxf(st[1][2], st[1][3]));
    float t2 = fmaxf(fmaxf(st[2][0], st[2][1]), fmaxf(st[2][2], st[2][3]));
    float t3 = fmaxf(fmaxf(st[3][0], st[3][1]), fmaxf(st[3][2], st[3][3]));
    float tm = fmaxf(fmaxf(t0, t1), fmaxf(t2, t3));
    tm = fmaxf(tm, __shfl_xor(tm, 16));
    tm = fmaxf(tm, __shfl_xor(tm, 32));
    float mnew = fmaxf(m_sm, tm);
    bool grew = tm > m_sm;

    // P = exp2(S - m), tree-summed
    float ps[4];
#pragma unroll
    for (int ni = 0; ni < 4; ni++) {
      float e0 = exp2f(st[ni][0] - mnew);
      float e1 = exp2f(st[ni][1] - mnew);
      float e2 = exp2f(st[ni][2] - mnew);
      float e3 = exp2f(st[ni][3] - mnew);
      st[ni][0] = e0; st[ni][1] = e1; st[ni][2] = e2; st[ni][3] = e3;
      ps[ni] = (e0 + e1) + (e2 + e3);
    }
    float psum = (ps[0] + ps[1]) + (ps[2] + ps[3]);
    psum += __shfl_xor(psum, 16);
    psum += __shfl_xor(psum, 32);
    l_sm = l_sm * (grew ? exp2f(m_sm - mnew) : 1.0f) + psum;
    m_sm = mnew;

    // redistribute new max to oacc-row layout; rescale oacc (skip if no-op)
    if (__any(grew)) {
#pragma unroll
      for (int r = 0; r < 4; r++) {
        float mn = __shfl(mnew, 4 * lg + r);  // lane 4*lg+r owns row 4*lg+r
        float corr = exp2f(m_acc[r] - mn);
        m_acc[r] = mn;
#pragma unroll
        for (int ni = 0; ni < 4; ni++) oacc[ni][r] *= corr;
      }
    }

    // P -> LDS via v_cvt_pk_bf16_f32 (src0 -> low half), 8B stores, swizzled
#pragma unroll
    for (int ni = 0; ni < 4; ni++) {
      unsigned p01, p23;
      asm("v_cvt_pk_bf16_f32 %0, %1, %2" : "=v"(p01) : "v"(st[ni][0]), "v"(st[ni][1]));
      asm("v_cvt_pk_bf16_f32 %0, %1, %2" : "=v"(p23) : "v"(st[ni][2]), "v"(st[ni][3]));
      uint2 pk; pk.x = p01; pk.y = p23;
      *reinterpret_cast<uint2*>(&p_lds[poff[ni]]) = pk;
    }

    // O += P @ V  (pa: wave-private p_lds rows; vb: staged V^T)
#pragma unroll
    for (int ks = 0; ks < 2; ks++) {
      bf16x8 pa = *reinterpret_cast<const bf16x8*>(&p_lds[paoff[ks]]);
      bf16x8 vb[4];
#pragma unroll
      for (int ni = 0; ni < 4; ni++)
        vb[ni] = *reinterpret_cast<const bf16x8*>(&vt_lds[cur][vboff[ks][ni]]);
      __builtin_amdgcn_s_setprio(1);
#pragma unroll
      for (int ni = 0; ni < 4; ni++)
        oacc[ni] = mfma16(pa, vb[ni], oacc[ni]);
      __builtin_amdgcn_s_setprio(0);
    }

    if (kt < 15) write_v(nxt);  // waits vmcnt for load_v data only
    asm volatile("s_waitcnt lgkmcnt(0)" ::: "memory");
    __builtin_amdgcn_s_barrier();
    __builtin_amdgcn_sched_barrier(0);
  }

  // epilogue: divide by row-sum (redistributed to oacc-row layout) and store
#pragma unroll
  for (int r = 0; r < 4; r++) {
    float lr = __shfl(l_sm, 4 * lg + r);
    float inv = 1.f / lr;
    int grow = tb + w * 16 + 4 * lg + r;
#pragma unroll
    for (int ni = 0; ni < 4; ni++) {
      int gcol = h * HD + ni * 16 + l16;
      O[(size_t)grow * CDIM + gcol] = f2bf(oacc[ni][r] * inv);
    }
  }
}

extern "C" void kernel_launch(void* const* d_in, const int* in_sizes, int n_in,
                              void* d_out, int out_size, void* d_ws, size_t ws_size,
                              hipStream_t stream) {
  const float* x     = (const float*)d_in[0];
  const float* pos   = (const float*)d_in[1];
  const float* gamma = (const float*)d_in[2];
  const float* beta  = (const float*)d_in[3];
  const float* Wq    = (const float*)d_in[4];
  const float* bq    = (const float*)d_in[5];
  const float* Wk    = (const float*)d_in[6];
  const float* bk    = (const float*)d_in[7];
  const float* Wv    = (const float*)d_in[8];
  const float* bv    = (const float*)d_in[9];
  const float* Wo    = (const float*)d_in[10];
  const float* bo    = (const float*)d_in[11];
  float* out = (float*)d_out;

  ushort_t* xn   = (ushort_t*)d_ws;                    // 8192*768
  ushort_t* wt   = xn + (size_t)TOK * CDIM;            // 3072*768 (q,k,v,o transposed)
  ushort_t* qkv  = wt + (size_t)3072 * CDIM;           // 8192*2304
  ushort_t* aout = qkv + (size_t)TOK * QKV_N;          // 8192*768

  ln_kernel<<<TOK, 256, 0, stream>>>(x, gamma, beta, xn);
  wtrans_kernel<<<dim3(24, 24, 4), dim3(32, 8), 0, stream>>>(Wq, Wk, Wv, Wo, wt);
  gemm_kernel<0><<<dim3(18, 64), 256, 0, stream>>>(xn, wt, bq, bk, bv, pos, qkv);
  attn_kernel<<<dim3(16, NH, 8), 256, 0, stream>>>(qkv, aout);
  gemm_kernel<1><<<dim3(6, 64), 256, 0, stream>>>(aout, wt + (size_t)QKV_N * CDIM,
                                                  bo, nullptr, nullptr, x, out);
}

// Round 9
// 211.656 us; speedup vs baseline: 1.2231x; 1.0112x over previous
//
#include <hip/hip_runtime.h>
#include <hip/hip_bf16.h>

#define TOK 8192
#define CDIM 768
#define NH 12
#define HD 64
#define QKV_N 2304
// 0.125 * log2(e): QK^T scale folded into Q, softmax runs in exp2 domain
#define QSCALE 0.18033688011f
// deferred-max reference (exp2 domain): P = 2^(S' - MREF) <= 1 for S' <= MREF
#define MREF 10.0f

typedef __attribute__((ext_vector_type(8))) short bf16x8;
typedef __attribute__((ext_vector_type(4))) float f32x4;
typedef unsigned short ushort_t;

__device__ __forceinline__ ushort_t f2bf(float f) {
  unsigned u = __float_as_uint(f);
  u += 0x7fffu + ((u >> 16) & 1u);
  return (ushort_t)(u >> 16);
}

__device__ __forceinline__ f32x4 mfma16(bf16x8 a, bf16x8 b, f32x4 c) {
  return __builtin_amdgcn_mfma_f32_16x16x32_bf16(a, b, c, 0, 0, 0);
}

// XOR swizzle for 8-chunk (64-col) bf16 LDS rows
__device__ __forceinline__ int swz(int r) { return (r ^ (r >> 3)) & 7; }

__device__ __forceinline__ void gload16(const void* g, void* l) {
  __builtin_amdgcn_global_load_lds(
      (const __attribute__((address_space(1))) unsigned int*)g,
      (__attribute__((address_space(3))) unsigned int*)l, 16, 0, 0);
}

// ---------------- LayerNorm: 1 block per token, fp32 stats, bf16 out ----------
__global__ __launch_bounds__(256) void ln_kernel(const float* __restrict__ x,
                                                 const float* __restrict__ gamma,
                                                 const float* __restrict__ beta,
                                                 ushort_t* __restrict__ xn) {
  int t = blockIdx.x;
  const float* row = x + (size_t)t * CDIM;
  float v[3];
  float s = 0.f, s2 = 0.f;
#pragma unroll
  for (int i = 0; i < 3; i++) {
    v[i] = row[threadIdx.x + 256 * i];
    s += v[i];
    s2 += v[i] * v[i];
  }
#pragma unroll
  for (int off = 32; off; off >>= 1) {
    s += __shfl_xor(s, off);
    s2 += __shfl_xor(s2, off);
  }
  __shared__ float red[8];
  int wid = threadIdx.x >> 6, lane = threadIdx.x & 63;
  if (lane == 0) { red[wid] = s; red[wid + 4] = s2; }
  __syncthreads();
  s = red[0] + red[1] + red[2] + red[3];
  s2 = red[4] + red[5] + red[6] + red[7];
  float mu = s * (1.f / CDIM);
  float var = s2 * (1.f / CDIM) - mu * mu;
  float rstd = rsqrtf(var + 1e-5f);
  ushort_t* orow = xn + (size_t)t * CDIM;
#pragma unroll
  for (int i = 0; i < 3; i++) {
    int c = threadIdx.x + 256 * i;
    orow[c] = f2bf((v[i] - mu) * rstd * gamma[c] + beta[c]);
  }
}

// -------- Weight transpose to bf16: wt[z][n][k] = W_z[k][n] ------------------
__global__ __launch_bounds__(256) void wtrans_kernel(const float* __restrict__ Wq,
                                                     const float* __restrict__ Wk,
                                                     const float* __restrict__ Wv,
                                                     const float* __restrict__ Wo,
                                                     ushort_t* __restrict__ wt) {
  const float* W = (blockIdx.z == 0) ? Wq : (blockIdx.z == 1) ? Wk
                   : (blockIdx.z == 2) ? Wv : Wo;
  __shared__ float tile[32][33];
  int tr = blockIdx.y, tc = blockIdx.x;
  int tx = threadIdx.x, ty = threadIdx.y;
#pragma unroll
  for (int j = 0; j < 4; j++) {
    int k = tr * 32 + ty + j * 8;
    tile[ty + j * 8][tx] = W[(size_t)k * CDIM + tc * 32 + tx];
  }
  __syncthreads();
  ushort_t* o = wt + (size_t)blockIdx.z * CDIM * CDIM;
#pragma unroll
  for (int j = 0; j < 4; j++) {
    int n = tc * 32 + ty + j * 8;
    o[(size_t)n * CDIM + tr * 32 + tx] = f2bf(tile[tx][ty + j * 8]);
  }
}

// -------- GEMM v3: T2 swizzle + overlapped double-buffer (issue-early) -------
// MODE 0: QKV fused (N=2304), bf16 out; Q third gets (+bias+pos)*QSCALE
// MODE 1: out-proj (N=768), fp32 out, +bias +fp32 residual
template <int MODE>
__global__ __launch_bounds__(256) void gemm_kernel(
    const ushort_t* __restrict__ A, const ushort_t* __restrict__ Bt,
    const float* __restrict__ b0, const float* __restrict__ b1,
    const float* __restrict__ b2, const float* __restrict__ extra,
    void* __restrict__ outp) {
  __shared__ __align__(16) ushort_t lds_a[2][128 * 64];
  __shared__ __align__(16) ushort_t lds_b[2][128 * 64];
  const int NB = (MODE == 0) ? 18 : 6;
  // XCD-chunked swizzle (nwg % 8 == 0 in both modes)
  int lin = blockIdx.y * NB + blockIdx.x;
  int nl = (lin & 7) * (NB * 8) + (lin >> 3);
  const int bn = nl % NB, bm = nl / NB;

  const int tid = threadIdx.x;
  const int lane = tid & 63, wid = tid >> 6;
  const int wr = wid >> 1, wc = wid & 1;
  const int l16 = lane & 15, lg = lane >> 4;
  f32x4 acc[4][4] = {};

  // hoisted swizzled read offsets
  int aoff[2][4], boff[2][4];
#pragma unroll
  for (int kk = 0; kk < 2; kk++) {
#pragma unroll
    for (int mi = 0; mi < 4; mi++) {
      int r = wr * 64 + mi * 16 + l16;
      aoff[kk][mi] = r * 64 + (((kk * 4 + lg) ^ swz(r)) & 7) * 8;
    }
#pragma unroll
    for (int ni = 0; ni < 4; ni++) {
      int r = wc * 64 + ni * 16 + l16;
      boff[kk][ni] = r * 64 + (((kk * 4 + lg) ^ swz(r)) & 7) * 8;
    }
  }

  auto stage = [&](int buf, int k0) {
#pragma unroll
    for (int i = 0; i < 4; i++) {
      int slot = i * 256 + tid;           // 1024 chunks of 16B per tile
      int row = slot >> 3, j = slot & 7;
      int c8 = ((j ^ swz(row)) & 7) * 8;  // pre-swizzled source column
      gload16(&A[(size_t)(bm * 128 + row) * CDIM + k0 + c8], &lds_a[buf][slot * 8]);
      gload16(&Bt[(size_t)(bn * 128 + row) * CDIM + k0 + c8], &lds_b[buf][slot * 8]);
    }
  };

  // prologue: stage tile 0, drain, barrier
  stage(0, 0);
  asm volatile("s_waitcnt vmcnt(0)" ::: "memory");
  __builtin_amdgcn_s_barrier();
  __builtin_amdgcn_sched_barrier(0);

  int cur = 0;
#pragma unroll 2
  for (int t = 0; t < 12; t++) {
    if (t < 11) stage(cur ^ 1, (t + 1) * 64);  // issue next tile early
#pragma unroll
    for (int kk = 0; kk < 2; kk++) {
      bf16x8 af[4], bfr[4];
#pragma unroll
      for (int mi = 0; mi < 4; mi++)
        af[mi] = *reinterpret_cast<const bf16x8*>(&lds_a[cur][aoff[kk][mi]]);
#pragma unroll
      for (int ni = 0; ni < 4; ni++)
        bfr[ni] = *reinterpret_cast<const bf16x8*>(&lds_b[cur][boff[kk][ni]]);
      __builtin_amdgcn_s_setprio(1);
#pragma unroll
      for (int mi = 0; mi < 4; mi++)
#pragma unroll
        for (int ni = 0; ni < 4; ni++)
          acc[mi][ni] = mfma16(af[mi], bfr[ni], acc[mi][ni]);
      __builtin_amdgcn_s_setprio(0);
    }
    // wait late: t+1 loads landed during compute; all reads of cur done
    asm volatile("s_waitcnt vmcnt(0) lgkmcnt(0)" ::: "memory");
    __builtin_amdgcn_s_barrier();
    __builtin_amdgcn_sched_barrier(0);
    cur ^= 1;
  }

#pragma unroll
  for (int mi = 0; mi < 4; mi++)
#pragma unroll
    for (int ni = 0; ni < 4; ni++)
#pragma unroll
      for (int r = 0; r < 4; r++) {
        int grow = bm * 128 + wr * 64 + mi * 16 + 4 * lg + r;
        int gcol = bn * 128 + wc * 64 + ni * 16 + l16;
        float v = acc[mi][ni][r];
        if (MODE == 0) {
          if (gcol < 768) {
            // Q: add bias + pos_embed, fold 1/sqrt(64)*log2(e) for exp2-softmax
            v = (v + b0[gcol] + extra[(size_t)grow * CDIM + gcol]) * QSCALE;
          } else if (gcol < 1536) {
            v += b1[gcol - 768];
          } else {
            v += b2[gcol - 1536];
          }
          ((ushort_t*)outp)[(size_t)grow * QKV_N + gcol] = f2bf(v);
        } else {
          v += b0[gcol] + extra[(size_t)grow * CDIM + gcol];
          ((float*)outp)[(size_t)grow * CDIM + gcol] = v;
        }
      }
}

// -------- Flash attention v8: deferred-max, zero per-iter cross-lane ops -----
// v5 skeleton (KVBLK=64, swapped QK^T, K reg-prefetch, V^T dbuf LDS).
// m init = MREF=10 (exp2 domain): P = 2^(S'-m) <= 1; per-lane compare +
// __any-guarded cold rescale path replaces per-iter shuffle reductions.
// l accumulated as per-lane partial; single cross-lane reduce in epilogue.
__global__ __launch_bounds__(256, 4) void attn_kernel(const ushort_t* __restrict__ QKV,
                                                      ushort_t* __restrict__ O) {
  // XCD-chunked swizzle over 1536 = 8 x 192: each XCD owns one batch b
  int lin = (blockIdx.z * NH + blockIdx.y) * 16 + blockIdx.x;
  int nl = (lin & 7) * 192 + (lin >> 3);
  const int qt = nl & 15;
  const int h = (nl >> 4) % NH;
  const int b = nl / 192;

  const int tid = threadIdx.x, lane = tid & 63, w = tid >> 6;
  const int l16 = lane & 15, lg = lane >> 4;
  const int tb = b * 1024 + qt * 64;
  const int co_q = h * HD, co_k = CDIM + h * HD, co_v = 2 * CDIM + h * HD;

  __shared__ __align__(16) ushort_t vt_lds[2][64 * 64];
  __shared__ __align__(16) ushort_t p_lds[64 * 64];

  // Q as B-fragment: rows q = w*16 + l16 (QSCALE folded in by QKV-GEMM)
  bf16x8 qf[2];
#pragma unroll
  for (int ds = 0; ds < 2; ds++)
    qf[ds] = *reinterpret_cast<const bf16x8*>(
        &QKV[(size_t)(tb + w * 16 + l16) * QKV_N + co_q + ds * 32 + 8 * lg]);

  const int myq = w * 16 + l16;  // this lane's softmax row (block-local)
  const int sq = swz(myq);
  float m_sm = MREF;       // per-lane running max ref (exp2 domain)
  float l_sm = 0.f;        // per-lane PARTIAL row sum (this lane's 16 kv cols)
  float m_acc[4];          // m in oacc-row layout (4*lg+r), for cold rescale
#pragma unroll
  for (int r = 0; r < 4; r++) m_acc[r] = MREF;
  f32x4 oacc[4] = {};

  // ---- hoisted LDS offsets (loop-invariant) ----
  int poff[4];
#pragma unroll
  for (int ni = 0; ni < 4; ni++)
    poff[ni] = myq * 64 + (lg & 1) * 4 + (((ni * 2 + (lg >> 1)) ^ sq) & 7) * 8;
  int paoff[2];
#pragma unroll
  for (int ks = 0; ks < 2; ks++)
    paoff[ks] = myq * 64 + (((ks * 4 + lg) ^ sq) & 7) * 8;
  int vboff[2][4];
#pragma unroll
  for (int ks = 0; ks < 2; ks++)
#pragma unroll
    for (int ni = 0; ni < 4; ni++) {
      int d = ni * 16 + l16;
      vboff[ks][ni] = d * 64 + (((ks * 4 + lg) ^ swz(d)) & 7) * 8;
    }

  // ---- paired-kv V staging: thread owns rows (kv0, kv0+1), d-chunk d0..d0+7
  const int kv0 = (tid >> 3) * 2, d0 = (tid & 7) * 8;
  const int sV = ((kv0 >> 3) ^ (d0 >> 3)) & 7;
  int voff[8];
#pragma unroll
  for (int u = 0; u < 8; u++)
    voff[u] = (d0 + u) * 64 + ((sV ^ u) & 7) * 8 + (kv0 & 7);
  const ushort_t* vsrc = QKV + (size_t)(b * 1024 + kv0) * QKV_N + co_v + d0;

  uint4 vr0, vr1;
  auto load_v = [&](int kt) {
    vr0 = *reinterpret_cast<const uint4*>(vsrc + (size_t)kt * 64 * QKV_N);
    vr1 = *reinterpret_cast<const uint4*>(vsrc + (size_t)kt * 64 * QKV_N + QKV_N);
  };
  auto write_v = [&](int buf) {
    const unsigned* w0 = reinterpret_cast<const unsigned*>(&vr0);
    const unsigned* w1 = reinterpret_cast<const unsigned*>(&vr1);
#pragma unroll
    for (int u = 0; u < 8; u++) {
      unsigned a = w0[u >> 1], c = w1[u >> 1];
      unsigned val = (u & 1) ? ((a >> 16) | (c & 0xffff0000u))
                             : ((a & 0xffffu) | (c << 16));
      *reinterpret_cast<unsigned*>(&vt_lds[buf][voff[u]]) = val;
    }
  };

  // ---- K fragments: direct from global (L2-hot), prefetched one tile ahead
  const ushort_t* kbase = QKV + (size_t)(b * 1024 + l16) * QKV_N + co_k + 8 * lg;
  bf16x8 kf[2][4];
  auto load_k = [&](int kt) {
#pragma unroll
    for (int ds = 0; ds < 2; ds++)
#pragma unroll
      for (int ni = 0; ni < 4; ni++)
        kf[ds][ni] = *reinterpret_cast<const bf16x8*>(
            kbase + ((size_t)kt * 64 + ni * 16) * QKV_N + ds * 32);
  };

  // prologue
  load_k(0);
  load_v(0);
  write_v(0);
  asm volatile("s_waitcnt lgkmcnt(0)" ::: "memory");
  __builtin_amdgcn_s_barrier();
  __builtin_amdgcn_sched_barrier(0);

  for (int kt = 0; kt < 16; kt++) {
    const int cur = kt & 1, nxt = cur ^ 1;
    if (kt < 15) load_v(kt + 1);  // issue early; consumed by write_v below

    // S^T = K Q^T : lane holds col q=l16, rows kv = ni*16 + 4*lg + r
    f32x4 st[4] = {};
    __builtin_amdgcn_s_setprio(1);
#pragma unroll
    for (int ds = 0; ds < 2; ds++)
#pragma unroll
      for (int ni = 0; ni < 4; ni++)
        st[ni] = mfma16(kf[ds][ni], qf[ds], st[ni]);
    __builtin_amdgcn_s_setprio(0);

    if (kt < 15) load_k(kt + 1);  // prefetch next K; latency hidden below

    // per-lane max of this lane's 16 values (no cross-lane)
    float t0 = fmaxf(fmaxf(st[0][0], st[0][1]), fmaxf(st[0][2], st[0][3]));
    float t1 = fmaxf(fmaxf(st[1][0], st[1][1]), fmaxf(st[1][2], st[1][3]));
    float t2 = fmaxf(fmaxf(st[2][0], st[2][1]), fmaxf(st[2][2], st[2][3]));
    float t3 = fmaxf(fmaxf(st[3][0], st[3][1]), fmaxf(st[3][2], st[3][3]));
    float tm = fmaxf(fmaxf(t0, t1), fmaxf(t2, t3));

    // deferred-max: rescale only if some lane exceeded the reference (cold)
    if (__any(tm > m_sm)) {
      float rm = fmaxf(tm, __shfl_xor(tm, 16));
      rm = fmaxf(rm, __shfl_xor(rm, 32));            // row-wide max
      float mnew = fmaxf(m_sm, rm);
      l_sm *= exp2f(m_sm - mnew);                     // row-lanes agree on m
      m_sm = mnew;
#pragma unroll
      for (int r = 0; r < 4; r++) {
        float mn = __shfl(mnew, 4 * lg + r);          // oacc-row layout
        float corr = exp2f(m_acc[r] - mn);
        m_acc[r] = mn;
#pragma unroll
        for (int ni = 0; ni < 4; ni++) oacc[ni][r] *= corr;
      }
    }

    // P = exp2(S - m) <= 1; accumulate per-lane partial sum (no shuffles)
    float ps[4];
#pragma unroll
    for (int ni = 0; ni < 4; ni++) {
      float e0 = exp2f(st[ni][0] - m_sm);
      float e1 = exp2f(st[ni][1] - m_sm);
      float e2 = exp2f(st[ni][2] - m_sm);
      float e3 = exp2f(st[ni][3] - m_sm);
      st[ni][0] = e0; st[ni][1] = e1; st[ni][2] = e2; st[ni][3] = e3;
      ps[ni] = (e0 + e1) + (e2 + e3);
    }
    l_sm += (ps[0] + ps[1]) + (ps[2] + ps[3]);

    // P -> LDS via v_cvt_pk_bf16_f32 (src0 -> low half), 8B stores, swizzled
#pragma unroll
    for (int ni = 0; ni < 4; ni++) {
      unsigned p01, p23;
      asm("v_cvt_pk_bf16_f32 %0, %1, %2" : "=v"(p01) : "v"(st[ni][0]), "v"(st[ni][1]));
      asm("v_cvt_pk_bf16_f32 %0, %1, %2" : "=v"(p23) : "v"(st[ni][2]), "v"(st[ni][3]));
      uint2 pk; pk.x = p01; pk.y = p23;
      *reinterpret_cast<uint2*>(&p_lds[poff[ni]]) = pk;
    }

    // O += P @ V  (pa: wave-private p_lds rows; vb: staged V^T)
#pragma unroll
    for (int ks = 0; ks < 2; ks++) {
      bf16x8 pa = *reinterpret_cast<const bf16x8*>(&p_lds[paoff[ks]]);
      bf16x8 vb[4];
#pragma unroll
      for (int ni = 0; ni < 4; ni++)
        vb[ni] = *reinterpret_cast<const bf16x8*>(&vt_lds[cur][vboff[ks][ni]]);
      __builtin_amdgcn_s_setprio(1);
#pragma unroll
      for (int ni = 0; ni < 4; ni++)
        oacc[ni] = mfma16(pa, vb[ni], oacc[ni]);
      __builtin_amdgcn_s_setprio(0);
    }

    if (kt < 15) write_v(nxt);  // waits vmcnt for load_v data only
    asm volatile("s_waitcnt lgkmcnt(0)" ::: "memory");
    __builtin_amdgcn_s_barrier();
    __builtin_amdgcn_sched_barrier(0);
  }

  // epilogue: complete the deferred row-sum reduce (the ONLY cross-lane
  // softmax ops in the kernel), then divide and store
  l_sm += __shfl_xor(l_sm, 16);
  l_sm += __shfl_xor(l_sm, 32);
#pragma unroll
  for (int r = 0; r < 4; r++) {
    float lr = __shfl(l_sm, 4 * lg + r);
    float inv = 1.f / lr;
    int grow = tb + w * 16 + 4 * lg + r;
#pragma unroll
    for (int ni = 0; ni < 4; ni++) {
      int gcol = h * HD + ni * 16 + l16;
      O[(size_t)grow * CDIM + gcol] = f2bf(oacc[ni][r] * inv);
    }
  }
}

extern "C" void kernel_launch(void* const* d_in, const int* in_sizes, int n_in,
                              void* d_out, int out_size, void* d_ws, size_t ws_size,
                              hipStream_t stream) {
  const float* x     = (const float*)d_in[0];
  const float* pos   = (const float*)d_in[1];
  const float* gamma = (const float*)d_in[2];
  const float* beta  = (const float*)d_in[3];
  const float* Wq    = (const float*)d_in[4];
  const float* bq    = (const float*)d_in[5];
  const float* Wk    = (const float*)d_in[6];
  const float* bk    = (const float*)d_in[7];
  const float* Wv    = (const float*)d_in[8];
  const float* bv    = (const float*)d_in[9];
  const float* Wo    = (const float*)d_in[10];
  const float* bo    = (const float*)d_in[11];
  float* out = (float*)d_out;

  ushort_t* xn   = (ushort_t*)d_ws;                    // 8192*768
  ushort_t* wt   = xn + (size_t)TOK * CDIM;            // 3072*768 (q,k,v,o transposed)
  ushort_t* qkv  = wt + (size_t)3072 * CDIM;           // 8192*2304
  ushort_t* aout = qkv + (size_t)TOK * QKV_N;          // 8192*768

  ln_kernel<<<TOK, 256, 0, stream>>>(x, gamma, beta, xn);
  wtrans_kernel<<<dim3(24, 24, 4), dim3(32, 8), 0, stream>>>(Wq, Wk, Wv, Wo, wt);
  gemm_kernel<0><<<dim3(18, 64), 256, 0, stream>>>(xn, wt, bq, bk, bv, pos, qkv);
  attn_kernel<<<dim3(16, NH, 8), 256, 0, stream>>>(qkv, aout);
  gemm_kernel<1><<<dim3(6, 64), 256, 0, stream>>>(aout, wt + (size_t)QKV_N * CDIM,
                                                  bo, nullptr, nullptr, x, out);
}

// Round 10
// 167.466 us; speedup vs baseline: 1.5458x; 1.2639x over previous
//
#include <hip/hip_runtime.h>
#include <hip/hip_bf16.h>

#define TOK 8192
#define CDIM 768
#define NH 12
#define HD 64
#define QKV_N 2304
// 0.125 * log2(e): QK^T scale folded into Q, softmax runs in exp2 domain
#define QSCALE 0.18033688011f
// deferred-max reference (exp2 domain): P = 2^(S' - MREF) <= 1 for S' <= MREF
#define MREF 10.0f

typedef __attribute__((ext_vector_type(8))) short bf16x8;
typedef __attribute__((ext_vector_type(4))) float f32x4;
typedef unsigned short ushort_t;

__device__ __forceinline__ ushort_t f2bf(float f) {
  unsigned u = __float_as_uint(f);
  u += 0x7fffu + ((u >> 16) & 1u);
  return (ushort_t)(u >> 16);
}

__device__ __forceinline__ f32x4 mfma16(bf16x8 a, bf16x8 b, f32x4 c) {
  return __builtin_amdgcn_mfma_f32_16x16x32_bf16(a, b, c, 0, 0, 0);
}

// XOR swizzle for 8-chunk (64-col) bf16 LDS rows
__device__ __forceinline__ int swz(int r) { return (r ^ (r >> 3)) & 7; }

__device__ __forceinline__ void gload16(const void* g, void* l) {
  __builtin_amdgcn_global_load_lds(
      (const __attribute__((address_space(1))) unsigned int*)g,
      (__attribute__((address_space(3))) unsigned int*)l, 16, 0, 0);
}

// ---------------- LayerNorm: 1 block per token, fp32 stats, bf16 out ----------
__global__ __launch_bounds__(256) void ln_kernel(const float* __restrict__ x,
                                                 const float* __restrict__ gamma,
                                                 const float* __restrict__ beta,
                                                 ushort_t* __restrict__ xn) {
  int t = blockIdx.x;
  const float* row = x + (size_t)t * CDIM;
  float v[3];
  float s = 0.f, s2 = 0.f;
#pragma unroll
  for (int i = 0; i < 3; i++) {
    v[i] = row[threadIdx.x + 256 * i];
    s += v[i];
    s2 += v[i] * v[i];
  }
#pragma unroll
  for (int off = 32; off; off >>= 1) {
    s += __shfl_xor(s, off);
    s2 += __shfl_xor(s2, off);
  }
  __shared__ float red[8];
  int wid = threadIdx.x >> 6, lane = threadIdx.x & 63;
  if (lane == 0) { red[wid] = s; red[wid + 4] = s2; }
  __syncthreads();
  s = red[0] + red[1] + red[2] + red[3];
  s2 = red[4] + red[5] + red[6] + red[7];
  float mu = s * (1.f / CDIM);
  float var = s2 * (1.f / CDIM) - mu * mu;
  float rstd = rsqrtf(var + 1e-5f);
  ushort_t* orow = xn + (size_t)t * CDIM;
#pragma unroll
  for (int i = 0; i < 3; i++) {
    int c = threadIdx.x + 256 * i;
    orow[c] = f2bf((v[i] - mu) * rstd * gamma[c] + beta[c]);
  }
}

// -------- Weight transpose to bf16: wt[z][n][k] = W_z[k][n] ------------------
__global__ __launch_bounds__(256) void wtrans_kernel(const float* __restrict__ Wq,
                                                     const float* __restrict__ Wk,
                                                     const float* __restrict__ Wv,
                                                     const float* __restrict__ Wo,
                                                     ushort_t* __restrict__ wt) {
  const float* W = (blockIdx.z == 0) ? Wq : (blockIdx.z == 1) ? Wk
                   : (blockIdx.z == 2) ? Wv : Wo;
  __shared__ float tile[32][33];
  int tr = blockIdx.y, tc = blockIdx.x;
  int tx = threadIdx.x, ty = threadIdx.y;
#pragma unroll
  for (int j = 0; j < 4; j++) {
    int k = tr * 32 + ty + j * 8;
    tile[ty + j * 8][tx] = W[(size_t)k * CDIM + tc * 32 + tx];
  }
  __syncthreads();
  ushort_t* o = wt + (size_t)blockIdx.z * CDIM * CDIM;
#pragma unroll
  for (int j = 0; j < 4; j++) {
    int n = tc * 32 + ty + j * 8;
    o[(size_t)n * CDIM + tr * 32 + tx] = f2bf(tile[tx][ty + j * 8]);
  }
}

// -------- GEMM v3: T2 swizzle + overlapped double-buffer (issue-early) -------
// MODE 0: QKV fused (N=2304), bf16 out; Q third gets (+bias+pos)*QSCALE
// MODE 1: out-proj (N=768), fp32 out, +bias +fp32 residual
template <int MODE>
__global__ __launch_bounds__(256) void gemm_kernel(
    const ushort_t* __restrict__ A, const ushort_t* __restrict__ Bt,
    const float* __restrict__ b0, const float* __restrict__ b1,
    const float* __restrict__ b2, const float* __restrict__ extra,
    void* __restrict__ outp) {
  __shared__ __align__(16) ushort_t lds_a[2][128 * 64];
  __shared__ __align__(16) ushort_t lds_b[2][128 * 64];
  const int NB = (MODE == 0) ? 18 : 6;
  // XCD-chunked swizzle (nwg % 8 == 0 in both modes)
  int lin = blockIdx.y * NB + blockIdx.x;
  int nl = (lin & 7) * (NB * 8) + (lin >> 3);
  const int bn = nl % NB, bm = nl / NB;

  const int tid = threadIdx.x;
  const int lane = tid & 63, wid = tid >> 6;
  const int wr = wid >> 1, wc = wid & 1;
  const int l16 = lane & 15, lg = lane >> 4;
  f32x4 acc[4][4] = {};

  // hoisted swizzled read offsets
  int aoff[2][4], boff[2][4];
#pragma unroll
  for (int kk = 0; kk < 2; kk++) {
#pragma unroll
    for (int mi = 0; mi < 4; mi++) {
      int r = wr * 64 + mi * 16 + l16;
      aoff[kk][mi] = r * 64 + (((kk * 4 + lg) ^ swz(r)) & 7) * 8;
    }
#pragma unroll
    for (int ni = 0; ni < 4; ni++) {
      int r = wc * 64 + ni * 16 + l16;
      boff[kk][ni] = r * 64 + (((kk * 4 + lg) ^ swz(r)) & 7) * 8;
    }
  }

  auto stage = [&](int buf, int k0) {
#pragma unroll
    for (int i = 0; i < 4; i++) {
      int slot = i * 256 + tid;           // 1024 chunks of 16B per tile
      int row = slot >> 3, j = slot & 7;
      int c8 = ((j ^ swz(row)) & 7) * 8;  // pre-swizzled source column
      gload16(&A[(size_t)(bm * 128 + row) * CDIM + k0 + c8], &lds_a[buf][slot * 8]);
      gload16(&Bt[(size_t)(bn * 128 + row) * CDIM + k0 + c8], &lds_b[buf][slot * 8]);
    }
  };

  // prologue: stage tile 0, drain, barrier
  stage(0, 0);
  asm volatile("s_waitcnt vmcnt(0)" ::: "memory");
  __builtin_amdgcn_s_barrier();
  __builtin_amdgcn_sched_barrier(0);

  int cur = 0;
#pragma unroll 2
  for (int t = 0; t < 12; t++) {
    if (t < 11) stage(cur ^ 1, (t + 1) * 64);  // issue next tile early
#pragma unroll
    for (int kk = 0; kk < 2; kk++) {
      bf16x8 af[4], bfr[4];
#pragma unroll
      for (int mi = 0; mi < 4; mi++)
        af[mi] = *reinterpret_cast<const bf16x8*>(&lds_a[cur][aoff[kk][mi]]);
#pragma unroll
      for (int ni = 0; ni < 4; ni++)
        bfr[ni] = *reinterpret_cast<const bf16x8*>(&lds_b[cur][boff[kk][ni]]);
      __builtin_amdgcn_s_setprio(1);
#pragma unroll
      for (int mi = 0; mi < 4; mi++)
#pragma unroll
        for (int ni = 0; ni < 4; ni++)
          acc[mi][ni] = mfma16(af[mi], bfr[ni], acc[mi][ni]);
      __builtin_amdgcn_s_setprio(0);
    }
    // wait late: t+1 loads landed during compute; all reads of cur done
    asm volatile("s_waitcnt vmcnt(0) lgkmcnt(0)" ::: "memory");
    __builtin_amdgcn_s_barrier();
    __builtin_amdgcn_sched_barrier(0);
    cur ^= 1;
  }

#pragma unroll
  for (int mi = 0; mi < 4; mi++)
#pragma unroll
    for (int ni = 0; ni < 4; ni++)
#pragma unroll
      for (int r = 0; r < 4; r++) {
        int grow = bm * 128 + wr * 64 + mi * 16 + 4 * lg + r;
        int gcol = bn * 128 + wc * 64 + ni * 16 + l16;
        float v = acc[mi][ni][r];
        if (MODE == 0) {
          if (gcol < 768) {
            // Q: add bias + pos_embed, fold 1/sqrt(64)*log2(e) for exp2-softmax
            v = (v + b0[gcol] + extra[(size_t)grow * CDIM + gcol]) * QSCALE;
          } else if (gcol < 1536) {
            v += b1[gcol - 768];
          } else {
            v += b2[gcol - 1536];
          }
          ((ushort_t*)outp)[(size_t)grow * QKV_N + gcol] = f2bf(v);
        } else {
          v += b0[gcol] + extra[(size_t)grow * CDIM + gcol];
          ((float*)outp)[(size_t)grow * CDIM + gcol] = v;
        }
      }
}

// -------- Flash attention v9: K-in-LDS (shared across waves), QBLK=128 -------
// Grid 768 = 8b x 12h x 8qt (exactly 3 blocks/CU x 256, one dispatch round).
// 4 waves x 2 m-tiles x 16 q-rows. K staged ONCE per block via gload16
// (pre-swizzled source, v3-proven layout), double-buffered; waves read kf
// via swizzled ds_read_b128 -- removes the 4x-redundant per-wave K global
// loads that dominated VMEM issue. Deferred-max softmax (v8, bit-identical).
__global__ __launch_bounds__(256, 3) void attn_kernel(const ushort_t* __restrict__ QKV,
                                                      ushort_t* __restrict__ O) {
  // b = blockIdx.x: HW round-robins consecutive x across XCDs -> XCD == batch
  const int b = blockIdx.x, h = blockIdx.y, qt = blockIdx.z;

  const int tid = threadIdx.x, lane = tid & 63, w = tid >> 6;
  const int l16 = lane & 15, lg = lane >> 4;
  const int tb = b * 1024 + qt * 128;
  const int co_q = h * HD, co_k = CDIM + h * HD, co_v = 2 * CDIM + h * HD;

  __shared__ __align__(16) ushort_t k_lds[2][64 * 64];   // K [kv][d] swizzled
  __shared__ __align__(16) ushort_t vt_lds[2][64 * 64];  // V^T [d][kv] swizzled
  __shared__ __align__(16) ushort_t p_lds[128 * 64];     // P [q][kv] swizzled

  // Q as B-fragment: 2 m-tiles, rows q = w*32 + mi*16 + l16 (QSCALE folded)
  bf16x8 qf[2][2];
#pragma unroll
  for (int mi = 0; mi < 2; mi++)
#pragma unroll
    for (int ds = 0; ds < 2; ds++)
      qf[mi][ds] = *reinterpret_cast<const bf16x8*>(
          &QKV[(size_t)(tb + w * 32 + mi * 16 + l16) * QKV_N + co_q + ds * 32 + 8 * lg]);

  float m_sm[2] = {MREF, MREF};  // per-lane running max ref (exp2 domain)
  float l_sm[2] = {0.f, 0.f};    // per-lane PARTIAL row sums
  float m_acc[2][4];             // m in oacc-row layout, for cold rescale
#pragma unroll
  for (int mi = 0; mi < 2; mi++)
#pragma unroll
    for (int r = 0; r < 4; r++) m_acc[mi][r] = MREF;
  f32x4 oacc[2][4] = {};

  // ---- hoisted LDS offsets (loop-invariant) ----
  int kfoff[2][4];  // K reads (A-frag): row kv = ni*16+l16, chunk ds*4+lg
#pragma unroll
  for (int ds = 0; ds < 2; ds++)
#pragma unroll
    for (int ni = 0; ni < 4; ni++) {
      int rr = ni * 16 + l16;
      kfoff[ds][ni] = rr * 64 + (((ds * 4 + lg) ^ swz(rr)) & 7) * 8;
    }
  int poff[2][4], paoff[2][2];
#pragma unroll
  for (int mi = 0; mi < 2; mi++) {
    int myq = w * 32 + mi * 16 + l16;
    int sq = swz(myq);
#pragma unroll
    for (int ni = 0; ni < 4; ni++)
      poff[mi][ni] = myq * 64 + (lg & 1) * 4 + (((ni * 2 + (lg >> 1)) ^ sq) & 7) * 8;
#pragma unroll
    for (int ks = 0; ks < 2; ks++)
      paoff[mi][ks] = myq * 64 + (((ks * 4 + lg) ^ sq) & 7) * 8;
  }
  int vboff[2][4];
#pragma unroll
  for (int ks = 0; ks < 2; ks++)
#pragma unroll
    for (int ni = 0; ni < 4; ni++) {
      int d = ni * 16 + l16;
      vboff[ks][ni] = d * 64 + (((ks * 4 + lg) ^ swz(d)) & 7) * 8;
    }

  // ---- K staging: 512 chunks of 16B, linear LDS dest, pre-swizzled source --
  auto stage_k = [&](int buf, int kt) {
    const int kv0 = kt * 64;
#pragma unroll
    for (int i = 0; i < 2; i++) {
      int slot = i * 256 + tid;
      int r = slot >> 3, j = slot & 7;
      int c = ((j ^ swz(r)) & 7) * 8;
      gload16(&QKV[(size_t)(b * 1024 + kv0 + r) * QKV_N + co_k + c],
              &k_lds[buf][slot * 8]);
    }
  };

  // ---- paired-kv V staging: thread owns rows (kv0, kv0+1), d-chunk d0..d0+7
  const int kv0 = (tid >> 3) * 2, d0 = (tid & 7) * 8;
  const int sV = ((kv0 >> 3) ^ (d0 >> 3)) & 7;
  int voff[8];
#pragma unroll
  for (int u = 0; u < 8; u++)
    voff[u] = (d0 + u) * 64 + ((sV ^ u) & 7) * 8 + (kv0 & 7);
  const ushort_t* vsrc = QKV + (size_t)(b * 1024 + kv0) * QKV_N + co_v + d0;

  uint4 vr0, vr1;
  auto load_v = [&](int kt) {
    vr0 = *reinterpret_cast<const uint4*>(vsrc + (size_t)kt * 64 * QKV_N);
    vr1 = *reinterpret_cast<const uint4*>(vsrc + (size_t)kt * 64 * QKV_N + QKV_N);
  };
  auto write_v = [&](int buf) {
    const unsigned* w0 = reinterpret_cast<const unsigned*>(&vr0);
    const unsigned* w1 = reinterpret_cast<const unsigned*>(&vr1);
#pragma unroll
    for (int u = 0; u < 8; u++) {
      unsigned a = w0[u >> 1], c = w1[u >> 1];
      unsigned val = (u & 1) ? ((a >> 16) | (c & 0xffff0000u))
                             : ((a & 0xffffu) | (c << 16));
      *reinterpret_cast<unsigned*>(&vt_lds[buf][voff[u]]) = val;
    }
  };

  // prologue
  stage_k(0, 0);
  load_v(0);
  write_v(0);
  asm volatile("s_waitcnt vmcnt(0) lgkmcnt(0)" ::: "memory");
  __builtin_amdgcn_s_barrier();
  __builtin_amdgcn_sched_barrier(0);

  for (int kt = 0; kt < 16; kt++) {
    const int cur = kt & 1, nxt = cur ^ 1;
    if (kt < 15) { stage_k(nxt, kt + 1); load_v(kt + 1); }  // issue early

    // K fragments from LDS (shared by all 4 waves)
    bf16x8 kf[2][4];
#pragma unroll
    for (int ds = 0; ds < 2; ds++)
#pragma unroll
      for (int ni = 0; ni < 4; ni++)
        kf[ds][ni] = *reinterpret_cast<const bf16x8*>(&k_lds[cur][kfoff[ds][ni]]);

#pragma unroll
    for (int mi = 0; mi < 2; mi++) {
      // S^T = K Q^T : lane holds col q, rows kv = ni*16 + 4*lg + r
      f32x4 st[4] = {};
      __builtin_amdgcn_s_setprio(1);
#pragma unroll
      for (int ds = 0; ds < 2; ds++)
#pragma unroll
        for (int ni = 0; ni < 4; ni++)
          st[ni] = mfma16(kf[ds][ni], qf[mi][ds], st[ni]);
      __builtin_amdgcn_s_setprio(0);

      // per-lane max of this lane's 16 values (no cross-lane)
      float t0 = fmaxf(fmaxf(st[0][0], st[0][1]), fmaxf(st[0][2], st[0][3]));
      float t1 = fmaxf(fmaxf(st[1][0], st[1][1]), fmaxf(st[1][2], st[1][3]));
      float t2 = fmaxf(fmaxf(st[2][0], st[2][1]), fmaxf(st[2][2], st[2][3]));
      float t3 = fmaxf(fmaxf(st[3][0], st[3][1]), fmaxf(st[3][2], st[3][3]));
      float tm = fmaxf(fmaxf(t0, t1), fmaxf(t2, t3));

      // deferred-max: rescale only if some lane exceeded the reference (cold)
      if (__any(tm > m_sm[mi])) {
        float rm = fmaxf(tm, __shfl_xor(tm, 16));
        rm = fmaxf(rm, __shfl_xor(rm, 32));          // row-wide max
        float mnew = fmaxf(m_sm[mi], rm);
        l_sm[mi] *= exp2f(m_sm[mi] - mnew);
        m_sm[mi] = mnew;
#pragma unroll
        for (int r = 0; r < 4; r++) {
          float mn = __shfl(mnew, 4 * lg + r);       // oacc-row layout
          float corr = exp2f(m_acc[mi][r] - mn);
          m_acc[mi][r] = mn;
#pragma unroll
          for (int ni = 0; ni < 4; ni++) oacc[mi][ni][r] *= corr;
        }
      }

      // P = exp2(S - m) <= 1; per-lane partial sum (no shuffles)
      float ps[4];
#pragma unroll
      for (int ni = 0; ni < 4; ni++) {
        float e0 = exp2f(st[ni][0] - m_sm[mi]);
        float e1 = exp2f(st[ni][1] - m_sm[mi]);
        float e2 = exp2f(st[ni][2] - m_sm[mi]);
        float e3 = exp2f(st[ni][3] - m_sm[mi]);
        st[ni][0] = e0; st[ni][1] = e1; st[ni][2] = e2; st[ni][3] = e3;
        ps[ni] = (e0 + e1) + (e2 + e3);
      }
      l_sm[mi] += (ps[0] + ps[1]) + (ps[2] + ps[3]);

      // P -> LDS via v_cvt_pk_bf16_f32, 8B stores, swizzled; wave-private rows
#pragma unroll
      for (int ni = 0; ni < 4; ni++) {
        unsigned p01, p23;
        asm("v_cvt_pk_bf16_f32 %0, %1, %2" : "=v"(p01) : "v"(st[ni][0]), "v"(st[ni][1]));
        asm("v_cvt_pk_bf16_f32 %0, %1, %2" : "=v"(p23) : "v"(st[ni][2]), "v"(st[ni][3]));
        uint2 pk; pk.x = p01; pk.y = p23;
        *reinterpret_cast<uint2*>(&p_lds[poff[mi][ni]]) = pk;
      }
    }

    // O += P @ V  (pa: wave-private p_lds rows; vb: staged V^T)
#pragma unroll
    for (int ks = 0; ks < 2; ks++) {
      bf16x8 pa0 = *reinterpret_cast<const bf16x8*>(&p_lds[paoff[0][ks]]);
      bf16x8 pa1 = *reinterpret_cast<const bf16x8*>(&p_lds[paoff[1][ks]]);
      bf16x8 vb[4];
#pragma unroll
      for (int ni = 0; ni < 4; ni++)
        vb[ni] = *reinterpret_cast<const bf16x8*>(&vt_lds[cur][vboff[ks][ni]]);
      __builtin_amdgcn_s_setprio(1);
#pragma unroll
      for (int ni = 0; ni < 4; ni++) {
        oacc[0][ni] = mfma16(pa0, vb[ni], oacc[0][ni]);
        oacc[1][ni] = mfma16(pa1, vb[ni], oacc[1][ni]);
      }
      __builtin_amdgcn_s_setprio(0);
    }

    if (kt < 15) write_v(nxt);  // waits vmcnt for its own loads only
    asm volatile("s_waitcnt vmcnt(0) lgkmcnt(0)" ::: "memory");
    __builtin_amdgcn_s_barrier();
    __builtin_amdgcn_sched_barrier(0);
  }

  // epilogue: deferred row-sum reduce (only cross-lane softmax ops), store
#pragma unroll
  for (int mi = 0; mi < 2; mi++) {
    float l = l_sm[mi];
    l += __shfl_xor(l, 16);
    l += __shfl_xor(l, 32);
#pragma unroll
    for (int r = 0; r < 4; r++) {
      float lr = __shfl(l, 4 * lg + r);
      float inv = 1.f / lr;
      int grow = tb + w * 32 + mi * 16 + 4 * lg + r;
#pragma unroll
      for (int ni = 0; ni < 4; ni++) {
        int gcol = h * HD + ni * 16 + l16;
        O[(size_t)grow * CDIM + gcol] = f2bf(oacc[mi][ni][r] * inv);
      }
    }
  }
}

extern "C" void kernel_launch(void* const* d_in, const int* in_sizes, int n_in,
                              void* d_out, int out_size, void* d_ws, size_t ws_size,
                              hipStream_t stream) {
  const float* x     = (const float*)d_in[0];
  const float* pos   = (const float*)d_in[1];
  const float* gamma = (const float*)d_in[2];
  const float* beta  = (const float*)d_in[3];
  const float* Wq    = (const float*)d_in[4];
  const float* bq    = (const float*)d_in[5];
  const float* Wk    = (const float*)d_in[6];
  const float* bk    = (const float*)d_in[7];
  const float* Wv    = (const float*)d_in[8];
  const float* bv    = (const float*)d_in[9];
  const float* Wo    = (const float*)d_in[10];
  const float* bo    = (const float*)d_in[11];
  float* out = (float*)d_out;

  ushort_t* xn   = (ushort_t*)d_ws;                    // 8192*768
  ushort_t* wt   = xn + (size_t)TOK * CDIM;            // 3072*768 (q,k,v,o transposed)
  ushort_t* qkv  = wt + (size_t)3072 * CDIM;           // 8192*2304
  ushort_t* aout = qkv + (size_t)TOK * QKV_N;          // 8192*768

  ln_kernel<<<TOK, 256, 0, stream>>>(x, gamma, beta, xn);
  wtrans_kernel<<<dim3(24, 24, 4), dim3(32, 8), 0, stream>>>(Wq, Wk, Wv, Wo, wt);
  gemm_kernel<0><<<dim3(18, 64), 256, 0, stream>>>(xn, wt, bq, bk, bv, pos, qkv);
  attn_kernel<<<dim3(8, NH, 8), 256, 0, stream>>>(qkv, aout);
  gemm_kernel<1><<<dim3(6, 64), 256, 0, stream>>>(aout, wt + (size_t)QKV_N * CDIM,
                                                  bo, nullptr, nullptr, x, out);
}